// Round 12
// baseline (70.611 us; speedup 1.0000x reference)
//
#include <hip/hip_runtime.h>
#include <hip/hip_cooperative_groups.h>

#define HW_BIG   1e10f
#define LOSS_EPS 1e-8f

typedef unsigned long long u64;
namespace cg = cooperative_groups;

// ---------------------------------------------------------------------------
// distance (in pixels) to nearest set bit in a 256-bit row mask rm[4] from
// position y. Returns 32768 if the row is empty. Exact. While-loops almost
// never iterate on dense masks (first-word hit is the common case).
// ---------------------------------------------------------------------------
__device__ __forceinline__ int row_nearest(const u64* rm, int y) {
    const int yw = y >> 6, yb = y & 63;
    int dd = 32768;
    u64 w = rm[yw] & (~0ULL >> (63 - yb));
    int j = yw;
    while (w == 0 && j > 0) w = rm[--j];
    if (w) dd = y - (j * 64 + 63 - __builtin_clzll(w));
    u64 w2 = rm[yw] & (~0ULL << yb);
    int j2 = yw;
    while (w2 == 0 && j2 < 3) w2 = rm[++j2];
    if (w2) { int du = (j2 * 64 + __builtin_ctzll(w2)) - y; dd = min(dd, du); }
    return dd;
}

// ---------------------------------------------------------------------------
// Single fused cooperative kernel: grid = nimg*32 blocks x 1024 threads
// (1 block/CU at B=8; co-resident: 16 waves/CU, ~50 KB LDS).
// Phase 1: vectorized mask build (float4, shfl nibble-pack) -> mv/ml in ws.
// grid.sync()
// Phase 2: R10's k2 body: boundary words in LDS (word-parallel, bit-exact),
//   while-loop row_nearest, padded G[256][9], merged A/B early-exit scan,
//   fused weight + focal BCE, deterministic 16-wave block partial.
// grid.sync()
// Phase 3: block 0 reduces nblk partials (fixed order, double) -> out.
// ---------------------------------------------------------------------------
__global__ void k_fused(const float* __restrict__ inp,
                        const float* __restrict__ tgt,
                        u64* __restrict__ mv,
                        u64* __restrict__ ml,
                        float* __restrict__ partials,
                        float* __restrict__ out,
                        double inv_count) {
    __shared__ u64 Mv[1024];       // [row x][yword] predicted-mask bits
    __shared__ u64 Ml[1024];       // label-mask bits
    __shared__ u64 Bib[1024];      // predicted-image boundary bits
    __shared__ u64 Blb[1024];      // label boundary bits
    __shared__ float G1[256][9];   // g_ib indexed [x'][yr], padded (9)
    __shared__ float G2[256][9];   // g_lb
    __shared__ float wsum[16];
    __shared__ double dsum[4];
    cg::grid_group grid = cg::this_grid();
    const int tid = threadIdx.x;

    // ---- Phase 1: mask build (waves 0-7 of each block; 512 quads/block) ----
    if (tid < 512) {
        const size_t gid4 = (size_t)blockIdx.x * 512 + tid;   // float4 index
        const float4 v4 = reinterpret_cast<const float4*>(inp)[gid4];
        const float4 t4 = reinterpret_cast<const float4*>(tgt)[gid4];
        const unsigned nv = (unsigned)(v4.x > 0.0f) | ((unsigned)(v4.y > 0.0f) << 1)
                          | ((unsigned)(v4.z > 0.0f) << 2) | ((unsigned)(v4.w > 0.0f) << 3);
        const unsigned nt = (unsigned)(t4.x > 0.5f) | ((unsigned)(t4.y > 0.5f) << 1)
                          | ((unsigned)(t4.z > 0.5f) << 2) | ((unsigned)(t4.w > 0.5f) << 3);
        const int sh = (tid & 15) * 4;
        u64 wv_ = ((u64)nv) << sh;
        u64 wt_ = ((u64)nt) << sh;
#pragma unroll
        for (int off = 1; off < 16; off <<= 1) {
            wv_ |= (u64)__shfl_xor((long long)wv_, off, 64);
            wt_ |= (u64)__shfl_xor((long long)wt_, off, 64);
        }
        if ((tid & 15) == 0) {
            mv[gid4 >> 4] = wv_;
            ml[gid4 >> 4] = wt_;
        }
    }
    grid.sync();

    // ---- Phase 2: boundary + DT + loss (R10 k2 body, bit-exact) ----
    const int img = blockIdx.x >> 5;
    const int y0  = (blockIdx.x & 31) * 8;
    const int x   = tid >> 2;           // 0..255
    const int yq  = tid & 3;            // 0..3
    const int ya  = y0 + yq;
    const int yv  = ya + 4;

    const size_t mbase = (size_t)img * 1024;
    Mv[tid] = mv[mbase + tid];
    Ml[tid] = ml[mbase + tid];
    const float va = inp[((size_t)img * 256 + x) * 256 + ya];
    const float vb = inp[((size_t)img * 256 + x) * 256 + yv];
    __syncthreads();

    {   // boundary words (zero-padded 4-neighbor rule)
        const int xr_ = tid >> 2, j = tid & 3;
        u64 own = Mv[tid];
        u64 up  = (xr_ > 0)   ? Mv[tid - 4] : 0ULL;
        u64 dn  = (xr_ < 255) ? Mv[tid + 4] : 0ULL;
        u64 lf  = (own << 1) | ((j > 0) ? (Mv[tid - 1] >> 63) : 0ULL);
        u64 rt  = (own >> 1) | ((j < 3) ? (Mv[tid + 1] << 63) : 0ULL);
        Bib[tid] = own & ~(up & dn & lf & rt);
        own = Ml[tid];
        up  = (xr_ > 0)   ? Ml[tid - 4] : 0ULL;
        dn  = (xr_ < 255) ? Ml[tid + 4] : 0ULL;
        lf  = (own << 1) | ((j > 0) ? (Ml[tid - 1] >> 63) : 0ULL);
        rt  = (own >> 1) | ((j < 3) ? (Ml[tid + 1] << 63) : 0ULL);
        Blb[tid] = own & ~(up & dn & lf & rt);
    }
    __syncthreads();

    const int ywa = ya >> 6, yba = ya & 63;
    const int ywb = yv >> 6, ybb = yv & 63;
    const bool fibA = (Bib[x * 4 + ywa] >> yba) & 1;
    const bool flbA = (Blb[x * 4 + ywa] >> yba) & 1;
    const float tA  = ((Ml[x * 4 + ywa] >> yba) & 1) ? 1.0f : 0.0f;
    const bool fibB = (Bib[x * 4 + ywb] >> ybb) & 1;
    const bool flbB = (Blb[x * 4 + ywb] >> ybb) & 1;
    const float tB  = ((Ml[x * 4 + ywb] >> ybb) & 1) ? 1.0f : 0.0f;

    const int d1a = row_nearest(&Bib[x * 4], ya);
    const int d2a = row_nearest(&Blb[x * 4], ya);
    const int d1b = row_nearest(&Bib[x * 4], yv);
    const int d2b = row_nearest(&Blb[x * 4], yv);
    const float g1a = (d1a > 255) ? HW_BIG : (float)(d1a * d1a);
    const float g2a = (d2a > 255) ? HW_BIG : (float)(d2a * d2a);
    const float g1b = (d1b > 255) ? HW_BIG : (float)(d1b * d1b);
    const float g2b = (d2b > 255) ? HW_BIG : (float)(d2b * d2b);
    G1[x][yq]     = g1a;
    G2[x][yq]     = g2a;
    G1[x][yq + 4] = g1b;
    G2[x][yq + 4] = g2b;
    __syncthreads();

    // merged exact early-exit outward scan over x' = x -+ d for both pixels
    float m1a = flbA ? g1a : 0.0f;
    float m2a = fibA ? g2a : 0.0f;
    float m1b = flbB ? g1b : 0.0f;
    float m2b = fibB ? g2b : 0.0f;
    for (int d = 1; d < 256; ++d) {
        const float fd2 = (float)(d * d);          // exact integer in f32
        if (fd2 >= m1a && fd2 >= m2a && fd2 >= m1b && fd2 >= m2b) break;
        const int xl = x - d;
        if (xl >= 0) {
            m1a = fminf(m1a, G1[xl][yq] + fd2);
            m2a = fminf(m2a, G2[xl][yq] + fd2);
            m1b = fminf(m1b, G1[xl][yq + 4] + fd2);
            m2b = fminf(m2b, G2[xl][yq + 4] + fd2);
        }
        const int xr = x + d;
        if (xr < 256) {
            m1a = fminf(m1a, G1[xr][yq] + fd2);
            m2a = fminf(m2a, G2[xr][yq] + fd2);
            m1b = fminf(m1b, G1[xr][yq + 4] + fd2);
            m2b = fminf(m2b, G2[xr][yq + 4] + fd2);
        }
    }

    // fused weight + focal BCE (GAMMA=1, THETA=1, SIGMA=1), fast intrinsics
    const float pa = 1.0f / (1.0f + __expf(-va));
    float wA = 1.0f;
    if (flbA) wA += __expf(-sqrtf(m1a));
    if (fibA) wA += __expf(-sqrtf(m2a));
    float lossA = wA * (-(1.0f - pa) * tA * __logf(pa + LOSS_EPS)
                        - pa * (1.0f - tA) * __logf(1.0f - pa + LOSS_EPS));

    const float pb = 1.0f / (1.0f + __expf(-vb));
    float wB = 1.0f;
    if (flbB) wB += __expf(-sqrtf(m1b));
    if (fibB) wB += __expf(-sqrtf(m2b));
    float lossB = wB * (-(1.0f - pb) * tB * __logf(pb + LOSS_EPS)
                        - pb * (1.0f - tB) * __logf(1.0f - pb + LOSS_EPS));

    float s = lossA + lossB;
#pragma unroll
    for (int off = 32; off > 0; off >>= 1) s += __shfl_down(s, off, 64);
    if ((tid & 63) == 0) wsum[tid >> 6] = s;
    __syncthreads();
    if (tid == 0) {
        float bs = 0.0f;
#pragma unroll
        for (int i = 0; i < 16; ++i) bs += wsum[i];
        partials[blockIdx.x] = bs;
    }
    grid.sync();

    // ---- Phase 3: block 0 reduces all partials (fixed order, double) ----
    if (blockIdx.x == 0 && tid < 256) {
        const int nblk = (int)gridDim.x;
        double ds = 0.0;
        for (int i = tid; i < nblk; i += 256) ds += (double)partials[i];
#pragma unroll
        for (int off = 32; off > 0; off >>= 1) ds += __shfl_down(ds, off, 64);
        if ((tid & 63) == 0) dsum[tid >> 6] = ds;
        __syncthreads();
        if (tid == 0)
            out[0] = (float)(((dsum[0] + dsum[1]) + (dsum[2] + dsum[3])) * inv_count);
    }
}

// ---------------------------------------------------------------------------
extern "C" void kernel_launch(void* const* d_in, const int* in_sizes, int n_in,
                              void* d_out, int out_size, void* d_ws, size_t ws_size,
                              hipStream_t stream) {
    const float* inp = (const float*)d_in[0];
    const float* tgt = (const float*)d_in[1];
    float* out = (float*)d_out;

    const int total = in_sizes[0];          // B*256*256
    const int nimg  = total / 65536;        // B = 8
    const int nblk  = nimg * 32;            // 256 blocks of 1024 threads

    char* ws = (char*)d_ws;
    u64*   mv    = (u64*)ws;                          // nimg*1024 u64 each
    u64*   ml    = mv + (size_t)nimg * 1024;
    float* parts = (float*)(ml + (size_t)nimg * 1024);

    double inv_count = 1.0 / (double)total;
    void* args[] = { (void*)&inp, (void*)&tgt, (void*)&mv, (void*)&ml,
                     (void*)&parts, (void*)&out, (void*)&inv_count };
    hipLaunchCooperativeKernel((void*)k_fused, dim3(nblk), dim3(1024),
                               args, 0, stream);
}

// Round 13
// 18.119 us; speedup vs baseline: 3.8970x; 3.8970x over previous
//
#include <hip/hip_runtime.h>

#define HW_BIG   1e10f
#define LOSS_EPS 1e-8f

typedef unsigned long long u64;

// ---------------------------------------------------------------------------
// distance (in pixels) to nearest set bit in a 256-bit row mask rm[4] from
// position y. Returns 32768 if the row is empty. Exact. While-loops almost
// never iterate on dense masks (first-word hit is the common case).
// ---------------------------------------------------------------------------
__device__ __forceinline__ int row_nearest(const u64* rm, int y) {
    const int yw = y >> 6, yb = y & 63;
    int dd = 32768;
    u64 w = rm[yw] & (~0ULL >> (63 - yb));
    int j = yw;
    while (w == 0 && j > 0) w = rm[--j];
    if (w) dd = y - (j * 64 + 63 - __builtin_clzll(w));
    u64 w2 = rm[yw] & (~0ULL << yb);
    int j2 = yw;
    while (w2 == 0 && j2 < 3) w2 = rm[++j2];
    if (w2) { int du = (j2 * 64 + __builtin_ctzll(w2)) - y; dd = min(dd, du); }
    return dd;
}

// ---------------------------------------------------------------------------
// Kernel 1: vectorized streaming mask builder. 256 thr/block, 4 px/thread
// via float4; nibble-pack into u64 words with a 4-step __shfl_xor OR-reduce.
// Block 0 zeroes out[0] for kernel 2's per-block atomicAdd (kernel-boundary
// visibility). Word layout: flat word index = pixel_index >> 6.
// ---------------------------------------------------------------------------
__global__ void k_masks(const float* __restrict__ inp,
                        const float* __restrict__ tgt,
                        u64* __restrict__ mv,
                        u64* __restrict__ ml,
                        float* __restrict__ out) {
    const int t = threadIdx.x;
    if (blockIdx.x == 0 && t == 0) out[0] = 0.0f;
    const size_t gid4 = (size_t)blockIdx.x * 256 + t;
    const float4 v4 = reinterpret_cast<const float4*>(inp)[gid4];
    const float4 t4 = reinterpret_cast<const float4*>(tgt)[gid4];
    const unsigned nv = (unsigned)(v4.x > 0.0f) | ((unsigned)(v4.y > 0.0f) << 1)
                      | ((unsigned)(v4.z > 0.0f) << 2) | ((unsigned)(v4.w > 0.0f) << 3);
    const unsigned nt = (unsigned)(t4.x > 0.5f) | ((unsigned)(t4.y > 0.5f) << 1)
                      | ((unsigned)(t4.z > 0.5f) << 2) | ((unsigned)(t4.w > 0.5f) << 3);
    const int sh = (t & 15) * 4;
    u64 wv_ = ((u64)nv) << sh;
    u64 wt_ = ((u64)nt) << sh;
#pragma unroll
    for (int off = 1; off < 16; off <<= 1) {
        wv_ |= (u64)__shfl_xor((long long)wv_, off, 64);
        wt_ |= (u64)__shfl_xor((long long)wt_, off, 64);
    }
    if ((t & 15) == 0) {
        mv[gid4 >> 4] = wv_;
        ml[gid4 >> 4] = wt_;
    }
}

// ---------------------------------------------------------------------------
// Kernel 2 (boundary + DT + loss + one atomic per block): identical to the
// R10 best kernel except the ending — one plain device-scope atomicAdd of
// the scaled block sum (no fences, no counters; inv_count = 2^-19 exact).
// ---------------------------------------------------------------------------
__global__ void k_dt_loss(const float* __restrict__ inp,
                          const u64* __restrict__ mv,
                          const u64* __restrict__ ml,
                          float* __restrict__ out,
                          float inv_count) {
    __shared__ u64 Mv[1024];       // [row x][yword] predicted-mask bits
    __shared__ u64 Ml[1024];       // label-mask bits
    __shared__ u64 Bib[1024];      // predicted-image boundary bits
    __shared__ u64 Blb[1024];      // label boundary bits
    __shared__ float G1[256][9];   // g_ib indexed [x'][yr], padded (9)
    __shared__ float G2[256][9];   // g_lb
    __shared__ float wsum[16];
    const int tid = threadIdx.x;
    const int img = blockIdx.x >> 5;
    const int y0  = (blockIdx.x & 31) * 8;
    const int x   = tid >> 2;           // 0..255
    const int yq  = tid & 3;            // 0..3
    const int ya  = y0 + yq;
    const int yv  = ya + 4;

    const size_t mbase = (size_t)img * 1024;
    Mv[tid] = mv[mbase + tid];
    Ml[tid] = ml[mbase + tid];
    // 4 consecutive lanes read 16 contiguous bytes (x uniform per lane quad)
    const float va = inp[((size_t)img * 256 + x) * 256 + ya];
    const float vb = inp[((size_t)img * 256 + x) * 256 + yv];
    __syncthreads();

    // boundary words (zero-padded 4-neighbor rule), bit-exact
    {
        const int xr_ = tid >> 2, j = tid & 3;
        u64 own = Mv[tid];
        u64 up  = (xr_ > 0)   ? Mv[tid - 4] : 0ULL;
        u64 dn  = (xr_ < 255) ? Mv[tid + 4] : 0ULL;
        u64 lf  = (own << 1) | ((j > 0) ? (Mv[tid - 1] >> 63) : 0ULL);
        u64 rt  = (own >> 1) | ((j < 3) ? (Mv[tid + 1] << 63) : 0ULL);
        Bib[tid] = own & ~(up & dn & lf & rt);
        own = Ml[tid];
        up  = (xr_ > 0)   ? Ml[tid - 4] : 0ULL;
        dn  = (xr_ < 255) ? Ml[tid + 4] : 0ULL;
        lf  = (own << 1) | ((j > 0) ? (Ml[tid - 1] >> 63) : 0ULL);
        rt  = (own >> 1) | ((j < 3) ? (Ml[tid + 1] << 63) : 0ULL);
        Blb[tid] = own & ~(up & dn & lf & rt);
    }
    __syncthreads();

    const int ywa = ya >> 6, yba = ya & 63;
    const int ywb = yv >> 6, ybb = yv & 63;
    const bool fibA = (Bib[x * 4 + ywa] >> yba) & 1;
    const bool flbA = (Blb[x * 4 + ywa] >> yba) & 1;
    const float tA  = ((Ml[x * 4 + ywa] >> yba) & 1) ? 1.0f : 0.0f;
    const bool fibB = (Bib[x * 4 + ywb] >> ybb) & 1;
    const bool flbB = (Blb[x * 4 + ywb] >> ybb) & 1;
    const float tB  = ((Ml[x * 4 + ywb] >> ybb) & 1) ? 1.0f : 0.0f;

    const int d1a = row_nearest(&Bib[x * 4], ya);
    const int d2a = row_nearest(&Blb[x * 4], ya);
    const int d1b = row_nearest(&Bib[x * 4], yv);
    const int d2b = row_nearest(&Blb[x * 4], yv);
    const float g1a = (d1a > 255) ? HW_BIG : (float)(d1a * d1a);
    const float g2a = (d2a > 255) ? HW_BIG : (float)(d2a * d2a);
    const float g1b = (d1b > 255) ? HW_BIG : (float)(d1b * d1b);
    const float g2b = (d2b > 255) ? HW_BIG : (float)(d2b * d2b);
    G1[x][yq]     = g1a;
    G2[x][yq]     = g2a;
    G1[x][yq + 4] = g1b;
    G2[x][yq + 4] = g2b;
    __syncthreads();

    // merged exact early-exit outward scan over x' = x -+ d for both pixels.
    // Lanes that don't consume a distance init to 0 so they never prolong
    // the scan. Break when d^2 >= all four running minima.
    float m1a = flbA ? g1a : 0.0f;
    float m2a = fibA ? g2a : 0.0f;
    float m1b = flbB ? g1b : 0.0f;
    float m2b = fibB ? g2b : 0.0f;
    for (int d = 1; d < 256; ++d) {
        const float fd2 = (float)(d * d);          // exact integer in f32
        if (fd2 >= m1a && fd2 >= m2a && fd2 >= m1b && fd2 >= m2b) break;
        const int xl = x - d;
        if (xl >= 0) {
            m1a = fminf(m1a, G1[xl][yq] + fd2);
            m2a = fminf(m2a, G2[xl][yq] + fd2);
            m1b = fminf(m1b, G1[xl][yq + 4] + fd2);
            m2b = fminf(m2b, G2[xl][yq + 4] + fd2);
        }
        const int xr = x + d;
        if (xr < 256) {
            m1a = fminf(m1a, G1[xr][yq] + fd2);
            m2a = fminf(m2a, G2[xr][yq] + fd2);
            m1b = fminf(m1b, G1[xr][yq + 4] + fd2);
            m2b = fminf(m2b, G2[xr][yq + 4] + fd2);
        }
    }

    // fused weight + focal BCE (GAMMA=1, THETA=1, SIGMA=1), fast intrinsics
    const float pa = 1.0f / (1.0f + __expf(-va));
    float wA = 1.0f;
    if (flbA) wA += __expf(-sqrtf(m1a));
    if (fibA) wA += __expf(-sqrtf(m2a));
    float lossA = wA * (-(1.0f - pa) * tA * __logf(pa + LOSS_EPS)
                        - pa * (1.0f - tA) * __logf(1.0f - pa + LOSS_EPS));

    const float pb = 1.0f / (1.0f + __expf(-vb));
    float wB = 1.0f;
    if (flbB) wB += __expf(-sqrtf(m1b));
    if (fibB) wB += __expf(-sqrtf(m2b));
    float lossB = wB * (-(1.0f - pb) * tB * __logf(pb + LOSS_EPS)
                        - pb * (1.0f - tB) * __logf(1.0f - pb + LOSS_EPS));

    // deterministic block reduction: wave shfl tree + 16 wave partials
    float s = lossA + lossB;
#pragma unroll
    for (int off = 32; off > 0; off >>= 1) s += __shfl_down(s, off, 64);
    if ((tid & 63) == 0) wsum[tid >> 6] = s;
    __syncthreads();
    if (tid == 0) {
        float bs = 0.0f;
#pragma unroll
        for (int i = 0; i < 16; ++i) bs += wsum[i];
        atomicAdd(out, bs * inv_count);   // one plain atomic per block
    }
}

// ---------------------------------------------------------------------------
extern "C" void kernel_launch(void* const* d_in, const int* in_sizes, int n_in,
                              void* d_out, int out_size, void* d_ws, size_t ws_size,
                              hipStream_t stream) {
    const float* inp = (const float*)d_in[0];
    const float* tgt = (const float*)d_in[1];
    float* out = (float*)d_out;

    const int total = in_sizes[0];          // B*256*256
    const int nimg  = total / 65536;        // B = 8
    const int nblk1 = total / 1024;         // 512 blocks (masks, 4 px/thread)
    const int nblk2 = nimg * 32;            // 256 blocks (DT+loss, 8 rows each)

    char* ws = (char*)d_ws;
    u64* mv = (u64*)ws;                               // nimg*1024 u64 each
    u64* ml = mv + (size_t)nimg * 1024;

    k_masks  <<<nblk1, 256,  0, stream>>>(inp, tgt, mv, ml, out);
    k_dt_loss<<<nblk2, 1024, 0, stream>>>(inp, mv, ml, out, 1.0f / (float)total);
}

// Round 14
// 17.476 us; speedup vs baseline: 4.0404x; 1.0368x over previous
//
#include <hip/hip_runtime.h>

#define HW_BIG   1e10f
#define LOSS_EPS 1e-8f

typedef unsigned long long u64;

// ---------------------------------------------------------------------------
// distance (in pixels) to nearest set bit in a 256-bit row mask rm[4] from
// position y. Returns 32768 if the row is empty. Exact. While-loops almost
// never iterate on dense masks (first-word hit is the common case).
// ---------------------------------------------------------------------------
__device__ __forceinline__ int row_nearest(const u64* rm, int y) {
    const int yw = y >> 6, yb = y & 63;
    int dd = 32768;
    u64 w = rm[yw] & (~0ULL >> (63 - yb));
    int j = yw;
    while (w == 0 && j > 0) w = rm[--j];
    if (w) dd = y - (j * 64 + 63 - __builtin_clzll(w));
    u64 w2 = rm[yw] & (~0ULL << yb);
    int j2 = yw;
    while (w2 == 0 && j2 < 3) w2 = rm[++j2];
    if (w2) { int du = (j2 * 64 + __builtin_ctzll(w2)) - y; dd = min(dd, du); }
    return dd;
}

// ---------------------------------------------------------------------------
// Kernel 1: vectorized streaming mask builder. 256 thr/block, 4 px/thread
// via float4; nibble-pack into u64 words with a 4-step __shfl_xor OR-reduce.
// Word layout: flat word index = pixel_index >> 6 (bit b = pixel 64w+b).
// ---------------------------------------------------------------------------
__global__ void k_masks(const float* __restrict__ inp,
                        const float* __restrict__ tgt,
                        u64* __restrict__ mv,
                        u64* __restrict__ ml) {
    const int t = threadIdx.x;
    const size_t gid4 = (size_t)blockIdx.x * 256 + t;
    const float4 v4 = reinterpret_cast<const float4*>(inp)[gid4];
    const float4 t4 = reinterpret_cast<const float4*>(tgt)[gid4];
    const unsigned nv = (unsigned)(v4.x > 0.0f) | ((unsigned)(v4.y > 0.0f) << 1)
                      | ((unsigned)(v4.z > 0.0f) << 2) | ((unsigned)(v4.w > 0.0f) << 3);
    const unsigned nt = (unsigned)(t4.x > 0.5f) | ((unsigned)(t4.y > 0.5f) << 1)
                      | ((unsigned)(t4.z > 0.5f) << 2) | ((unsigned)(t4.w > 0.5f) << 3);
    const int sh = (t & 15) * 4;
    u64 wv_ = ((u64)nv) << sh;
    u64 wt_ = ((u64)nt) << sh;
#pragma unroll
    for (int off = 1; off < 16; off <<= 1) {
        wv_ |= (u64)__shfl_xor((long long)wv_, off, 64);
        wt_ |= (u64)__shfl_xor((long long)wt_, off, 64);
    }
    if ((t & 15) == 0) {
        mv[gid4 >> 4] = wv_;
        ml[gid4 >> 4] = wt_;
    }
}

// ---------------------------------------------------------------------------
// Kernel 2 (boundary + DT + loss, 8 y-rows/block, ADJACENT pixel pairs):
// block = (img, 8 y-rows), 1024 threads = (x = tid>>2, yq = tid&3); each
// thread handles pixels (x, y0+2yq) and (x, y0+2yq+1) -> va/vb via ONE
// float2 load; both g's packed in float2 GG[256][5] -> scan body reads 4
// ds_read_b64 instead of 16 ds_read_b32. Same candidate set, bit-exact.
// ---------------------------------------------------------------------------
__global__ void k_dt_loss(const float* __restrict__ inp,
                          const u64* __restrict__ mv,
                          const u64* __restrict__ ml,
                          float* __restrict__ partials) {
    __shared__ u64 Mv[1024];        // [row x][yword] predicted-mask bits
    __shared__ u64 Ml[1024];        // label-mask bits
    __shared__ u64 Bib[1024];       // predicted-image boundary bits
    __shared__ u64 Blb[1024];       // label boundary bits
    __shared__ float2 GG1[256][5];  // (g_ib for ya, yv) indexed [x'][yq], pad 5
    __shared__ float2 GG2[256][5];  // (g_lb for ya, yv)
    __shared__ float wsum[16];
    const int tid = threadIdx.x;
    const int img = blockIdx.x >> 5;
    const int y0  = (blockIdx.x & 31) * 8;
    const int x   = tid >> 2;           // 0..255
    const int yq  = tid & 3;            // 0..3
    const int ya  = y0 + 2 * yq;        // even
    const int yv  = ya + 1;             // adjacent (same 64-bit word as ya)

    const size_t mbase = (size_t)img * 1024;
    Mv[tid] = mv[mbase + tid];
    Ml[tid] = ml[mbase + tid];
    // one float2 load covers both pixels; quad reads 32 contiguous bytes
    const float2 vv = reinterpret_cast<const float2*>(inp)
                          [(((size_t)img * 256 + x) * 256 + ya) >> 1];
    const float va = vv.x, vb = vv.y;
    __syncthreads();

    // boundary words (zero-padded 4-neighbor rule), bit-exact
    {
        const int xr_ = tid >> 2, j = tid & 3;
        u64 own = Mv[tid];
        u64 up  = (xr_ > 0)   ? Mv[tid - 4] : 0ULL;
        u64 dn  = (xr_ < 255) ? Mv[tid + 4] : 0ULL;
        u64 lf  = (own << 1) | ((j > 0) ? (Mv[tid - 1] >> 63) : 0ULL);
        u64 rt  = (own >> 1) | ((j < 3) ? (Mv[tid + 1] << 63) : 0ULL);
        Bib[tid] = own & ~(up & dn & lf & rt);
        own = Ml[tid];
        up  = (xr_ > 0)   ? Ml[tid - 4] : 0ULL;
        dn  = (xr_ < 255) ? Ml[tid + 4] : 0ULL;
        lf  = (own << 1) | ((j > 0) ? (Ml[tid - 1] >> 63) : 0ULL);
        rt  = (own >> 1) | ((j < 3) ? (Ml[tid + 1] << 63) : 0ULL);
        Blb[tid] = own & ~(up & dn & lf & rt);
    }
    __syncthreads();

    // ya and yv always share one 64-bit word (8-aligned block of 8 rows)
    const int yw = ya >> 6, yba = ya & 63, ybb = yv & 63;
    const u64 wib = Bib[x * 4 + yw];
    const u64 wlb = Blb[x * 4 + yw];
    const u64 wml = Ml[x * 4 + yw];
    const bool fibA = (wib >> yba) & 1, fibB = (wib >> ybb) & 1;
    const bool flbA = (wlb >> yba) & 1, flbB = (wlb >> ybb) & 1;
    const float tA  = ((wml >> yba) & 1) ? 1.0f : 0.0f;
    const float tB  = ((wml >> ybb) & 1) ? 1.0f : 0.0f;

    const int d1a = row_nearest(&Bib[x * 4], ya);
    const int d2a = row_nearest(&Blb[x * 4], ya);
    const int d1b = row_nearest(&Bib[x * 4], yv);
    const int d2b = row_nearest(&Blb[x * 4], yv);
    const float g1a = (d1a > 255) ? HW_BIG : (float)(d1a * d1a);
    const float g2a = (d2a > 255) ? HW_BIG : (float)(d2a * d2a);
    const float g1b = (d1b > 255) ? HW_BIG : (float)(d1b * d1b);
    const float g2b = (d2b > 255) ? HW_BIG : (float)(d2b * d2b);
    GG1[x][yq] = make_float2(g1a, g1b);
    GG2[x][yq] = make_float2(g2a, g2b);
    __syncthreads();

    // merged exact early-exit outward scan over x' = x -+ d for both pixels.
    // Lanes that don't consume a distance init to 0 so they never prolong
    // the scan. Break when d^2 >= all four running minima.
    float m1a = flbA ? g1a : 0.0f;
    float m2a = fibA ? g2a : 0.0f;
    float m1b = flbB ? g1b : 0.0f;
    float m2b = fibB ? g2b : 0.0f;
    for (int d = 1; d < 256; ++d) {
        const float fd2 = (float)(d * d);          // exact integer in f32
        if (fd2 >= m1a && fd2 >= m2a && fd2 >= m1b && fd2 >= m2b) break;
        const int xl = x - d;
        if (xl >= 0) {
            const float2 a = GG1[xl][yq];
            const float2 b = GG2[xl][yq];
            m1a = fminf(m1a, a.x + fd2);
            m1b = fminf(m1b, a.y + fd2);
            m2a = fminf(m2a, b.x + fd2);
            m2b = fminf(m2b, b.y + fd2);
        }
        const int xr = x + d;
        if (xr < 256) {
            const float2 a = GG1[xr][yq];
            const float2 b = GG2[xr][yq];
            m1a = fminf(m1a, a.x + fd2);
            m1b = fminf(m1b, a.y + fd2);
            m2a = fminf(m2a, b.x + fd2);
            m2b = fminf(m2b, b.y + fd2);
        }
    }

    // fused weight + focal BCE (GAMMA=1, THETA=1, SIGMA=1), fast intrinsics
    const float pa = 1.0f / (1.0f + __expf(-va));
    float wA = 1.0f;
    if (flbA) wA += __expf(-sqrtf(m1a));
    if (fibA) wA += __expf(-sqrtf(m2a));
    float lossA = wA * (-(1.0f - pa) * tA * __logf(pa + LOSS_EPS)
                        - pa * (1.0f - tA) * __logf(1.0f - pa + LOSS_EPS));

    const float pb = 1.0f / (1.0f + __expf(-vb));
    float wB = 1.0f;
    if (flbB) wB += __expf(-sqrtf(m1b));
    if (fibB) wB += __expf(-sqrtf(m2b));
    float lossB = wB * (-(1.0f - pb) * tB * __logf(pb + LOSS_EPS)
                        - pb * (1.0f - tB) * __logf(1.0f - pb + LOSS_EPS));

    // deterministic block reduction: wave shfl tree + 16 wave partials
    float s = lossA + lossB;
#pragma unroll
    for (int off = 32; off > 0; off >>= 1) s += __shfl_down(s, off, 64);
    if ((tid & 63) == 0) wsum[tid >> 6] = s;
    __syncthreads();
    if (tid == 0) {
        float bs = 0.0f;
#pragma unroll
        for (int i = 0; i < 16; ++i) bs += wsum[i];
        partials[blockIdx.x] = bs;
    }
}

// ---------------------------------------------------------------------------
// Kernel 3: reduce partials -> mean (single block, fixed order, double accum)
// ---------------------------------------------------------------------------
__global__ void k_reduce(const float* __restrict__ partials, int n,
                         float* __restrict__ out, double inv_count) {
    __shared__ double sw[4];
    const int tid = threadIdx.x;
    double s = 0.0;
    for (int i = tid; i < n; i += 256) s += (double)partials[i];
#pragma unroll
    for (int off = 32; off > 0; off >>= 1) s += __shfl_down(s, off, 64);
    const int lane = tid & 63, wv = tid >> 6;
    if (lane == 0) sw[wv] = s;
    __syncthreads();
    if (tid == 0) out[0] = (float)(((sw[0] + sw[1]) + (sw[2] + sw[3])) * inv_count);
}

// ---------------------------------------------------------------------------
extern "C" void kernel_launch(void* const* d_in, const int* in_sizes, int n_in,
                              void* d_out, int out_size, void* d_ws, size_t ws_size,
                              hipStream_t stream) {
    const float* inp = (const float*)d_in[0];
    const float* tgt = (const float*)d_in[1];
    float* out = (float*)d_out;

    const int total = in_sizes[0];          // B*256*256
    const int nimg  = total / 65536;        // B = 8
    const int nblk1 = total / 1024;         // 512 blocks (masks, 4 px/thread)
    const int nblk2 = nimg * 32;            // 256 blocks (DT+loss, 8 rows each)

    char* ws = (char*)d_ws;
    u64*   mv    = (u64*)ws;                          // nimg*1024 u64 each
    u64*   ml    = mv + (size_t)nimg * 1024;
    float* parts = (float*)(ml + (size_t)nimg * 1024);

    k_masks  <<<nblk1, 256,  0, stream>>>(inp, tgt, mv, ml);
    k_dt_loss<<<nblk2, 1024, 0, stream>>>(inp, mv, ml, parts);
    k_reduce <<<1,     256,  0, stream>>>(parts, nblk2, out, 1.0 / (double)total);
}

// Round 15
// 17.279 us; speedup vs baseline: 4.0866x; 1.0114x over previous
//
#include <hip/hip_runtime.h>

#define HW_BIG   1e10f
#define LOSS_EPS 1e-8f

typedef unsigned long long u64;

// ---------------------------------------------------------------------------
// distance (in pixels) to nearest set bit in a 256-bit row mask rm[4] from
// position y. Returns 32768 if the row is empty. Exact. While-loops almost
// never iterate on dense masks (first-word hit is the common case).
// ---------------------------------------------------------------------------
__device__ __forceinline__ int row_nearest(const u64* rm, int y) {
    const int yw = y >> 6, yb = y & 63;
    int dd = 32768;
    u64 w = rm[yw] & (~0ULL >> (63 - yb));
    int j = yw;
    while (w == 0 && j > 0) w = rm[--j];
    if (w) dd = y - (j * 64 + 63 - __builtin_clzll(w));
    u64 w2 = rm[yw] & (~0ULL << yb);
    int j2 = yw;
    while (w2 == 0 && j2 < 3) w2 = rm[++j2];
    if (w2) { int du = (j2 * 64 + __builtin_ctzll(w2)) - y; dd = min(dd, du); }
    return dd;
}

// ---------------------------------------------------------------------------
// Kernel 1: vectorized streaming mask builder. 256 thr/block, 4 px/thread
// via float4; nibble-pack into u64 words with a 4-step __shfl_xor OR-reduce.
// Word layout: flat word index = pixel_index >> 6 (bit b = pixel 64w+b).
// ---------------------------------------------------------------------------
__global__ void k_masks(const float* __restrict__ inp,
                        const float* __restrict__ tgt,
                        u64* __restrict__ mv,
                        u64* __restrict__ ml) {
    const int t = threadIdx.x;
    const size_t gid4 = (size_t)blockIdx.x * 256 + t;
    const float4 v4 = reinterpret_cast<const float4*>(inp)[gid4];
    const float4 t4 = reinterpret_cast<const float4*>(tgt)[gid4];
    const unsigned nv = (unsigned)(v4.x > 0.0f) | ((unsigned)(v4.y > 0.0f) << 1)
                      | ((unsigned)(v4.z > 0.0f) << 2) | ((unsigned)(v4.w > 0.0f) << 3);
    const unsigned nt = (unsigned)(t4.x > 0.5f) | ((unsigned)(t4.y > 0.5f) << 1)
                      | ((unsigned)(t4.z > 0.5f) << 2) | ((unsigned)(t4.w > 0.5f) << 3);
    const int sh = (t & 15) * 4;
    u64 wv_ = ((u64)nv) << sh;
    u64 wt_ = ((u64)nt) << sh;
#pragma unroll
    for (int off = 1; off < 16; off <<= 1) {
        wv_ |= (u64)__shfl_xor((long long)wv_, off, 64);
        wt_ |= (u64)__shfl_xor((long long)wt_, off, 64);
    }
    if ((t & 15) == 0) {
        mv[gid4 >> 4] = wv_;
        ml[gid4 >> 4] = wt_;
    }
}

// ---------------------------------------------------------------------------
// Kernel 2 (boundary + DT + loss, 8 y-rows/block): block = (img, 8 y-rows),
// 1024 threads = (x = tid>>2, yq = tid&3); pixels (x,y0+yq) and (x,y0+yq+4).
// Stage whole-image mask words -> boundary words in LDS (word-parallel,
// bit-exact) -> while-loop row_nearest (cheap common case) -> G[256][9]
// padded (2-way bank aliasing = free) -> MERGED A/B early-exit outward scan
// (one loop, shared break; length = max not sum) -> fused weight + focal BCE
// (fast __expf/__logf) -> deterministic 16-wave reduction.
// ---------------------------------------------------------------------------
__global__ void k_dt_loss(const float* __restrict__ inp,
                          const u64* __restrict__ mv,
                          const u64* __restrict__ ml,
                          float* __restrict__ partials) {
    __shared__ u64 Mv[1024];       // [row x][yword] predicted-mask bits
    __shared__ u64 Ml[1024];       // label-mask bits
    __shared__ u64 Bib[1024];      // predicted-image boundary bits
    __shared__ u64 Blb[1024];      // label boundary bits
    __shared__ float G1[256][9];   // g_ib indexed [x'][yr], padded (9)
    __shared__ float G2[256][9];   // g_lb
    __shared__ float wsum[16];
    const int tid = threadIdx.x;
    const int img = blockIdx.x >> 5;
    const int y0  = (blockIdx.x & 31) * 8;
    const int x   = tid >> 2;           // 0..255
    const int yq  = tid & 3;            // 0..3
    const int ya  = y0 + yq;
    const int yv  = ya + 4;

    const size_t mbase = (size_t)img * 1024;
    Mv[tid] = mv[mbase + tid];
    Ml[tid] = ml[mbase + tid];
    // 4 consecutive lanes read 16 contiguous bytes (x uniform per lane quad)
    const float va = inp[((size_t)img * 256 + x) * 256 + ya];
    const float vb = inp[((size_t)img * 256 + x) * 256 + yv];
    __syncthreads();

    // boundary words (zero-padded 4-neighbor rule), bit-exact
    {
        const int xr_ = tid >> 2, j = tid & 3;
        u64 own = Mv[tid];
        u64 up  = (xr_ > 0)   ? Mv[tid - 4] : 0ULL;
        u64 dn  = (xr_ < 255) ? Mv[tid + 4] : 0ULL;
        u64 lf  = (own << 1) | ((j > 0) ? (Mv[tid - 1] >> 63) : 0ULL);
        u64 rt  = (own >> 1) | ((j < 3) ? (Mv[tid + 1] << 63) : 0ULL);
        Bib[tid] = own & ~(up & dn & lf & rt);
        own = Ml[tid];
        up  = (xr_ > 0)   ? Ml[tid - 4] : 0ULL;
        dn  = (xr_ < 255) ? Ml[tid + 4] : 0ULL;
        lf  = (own << 1) | ((j > 0) ? (Ml[tid - 1] >> 63) : 0ULL);
        rt  = (own >> 1) | ((j < 3) ? (Ml[tid + 1] << 63) : 0ULL);
        Blb[tid] = own & ~(up & dn & lf & rt);
    }
    __syncthreads();

    const int ywa = ya >> 6, yba = ya & 63;
    const int ywb = yv >> 6, ybb = yv & 63;
    const bool fibA = (Bib[x * 4 + ywa] >> yba) & 1;
    const bool flbA = (Blb[x * 4 + ywa] >> yba) & 1;
    const float tA  = ((Ml[x * 4 + ywa] >> yba) & 1) ? 1.0f : 0.0f;
    const bool fibB = (Bib[x * 4 + ywb] >> ybb) & 1;
    const bool flbB = (Blb[x * 4 + ywb] >> ybb) & 1;
    const float tB  = ((Ml[x * 4 + ywb] >> ybb) & 1) ? 1.0f : 0.0f;

    const int d1a = row_nearest(&Bib[x * 4], ya);
    const int d2a = row_nearest(&Blb[x * 4], ya);
    const int d1b = row_nearest(&Bib[x * 4], yv);
    const int d2b = row_nearest(&Blb[x * 4], yv);
    const float g1a = (d1a > 255) ? HW_BIG : (float)(d1a * d1a);
    const float g2a = (d2a > 255) ? HW_BIG : (float)(d2a * d2a);
    const float g1b = (d1b > 255) ? HW_BIG : (float)(d1b * d1b);
    const float g2b = (d2b > 255) ? HW_BIG : (float)(d2b * d2b);
    G1[x][yq]     = g1a;
    G2[x][yq]     = g2a;
    G1[x][yq + 4] = g1b;
    G2[x][yq + 4] = g2b;
    __syncthreads();

    // merged exact early-exit outward scan over x' = x -+ d for BOTH pixels.
    // Lanes that don't consume a distance (m1 used only where flb, m2 where
    // fib) init to 0 so they never prolong the scan. Break when d^2 >= all 4.
    float m1a = flbA ? g1a : 0.0f;
    float m2a = fibA ? g2a : 0.0f;
    float m1b = flbB ? g1b : 0.0f;
    float m2b = fibB ? g2b : 0.0f;
    for (int d = 1; d < 256; ++d) {
        const float fd2 = (float)(d * d);          // exact integer in f32
        if (fd2 >= m1a && fd2 >= m2a && fd2 >= m1b && fd2 >= m2b) break;
        const int xl = x - d;
        if (xl >= 0) {
            m1a = fminf(m1a, G1[xl][yq] + fd2);
            m2a = fminf(m2a, G2[xl][yq] + fd2);
            m1b = fminf(m1b, G1[xl][yq + 4] + fd2);
            m2b = fminf(m2b, G2[xl][yq + 4] + fd2);
        }
        const int xr = x + d;
        if (xr < 256) {
            m1a = fminf(m1a, G1[xr][yq] + fd2);
            m2a = fminf(m2a, G2[xr][yq] + fd2);
            m1b = fminf(m1b, G1[xr][yq + 4] + fd2);
            m2b = fminf(m2b, G2[xr][yq + 4] + fd2);
        }
    }

    // fused weight + focal BCE (GAMMA=1, THETA=1, SIGMA=1), fast intrinsics
    const float pa = 1.0f / (1.0f + __expf(-va));
    float wA = 1.0f;
    if (flbA) wA += __expf(-sqrtf(m1a));
    if (fibA) wA += __expf(-sqrtf(m2a));
    float lossA = wA * (-(1.0f - pa) * tA * __logf(pa + LOSS_EPS)
                        - pa * (1.0f - tA) * __logf(1.0f - pa + LOSS_EPS));

    const float pb = 1.0f / (1.0f + __expf(-vb));
    float wB = 1.0f;
    if (flbB) wB += __expf(-sqrtf(m1b));
    if (fibB) wB += __expf(-sqrtf(m2b));
    float lossB = wB * (-(1.0f - pb) * tB * __logf(pb + LOSS_EPS)
                        - pb * (1.0f - tB) * __logf(1.0f - pb + LOSS_EPS));

    // deterministic block reduction: wave shfl tree + 16 wave partials
    float s = lossA + lossB;
#pragma unroll
    for (int off = 32; off > 0; off >>= 1) s += __shfl_down(s, off, 64);
    if ((tid & 63) == 0) wsum[tid >> 6] = s;
    __syncthreads();
    if (tid == 0) {
        float bs = 0.0f;
#pragma unroll
        for (int i = 0; i < 16; ++i) bs += wsum[i];
        partials[blockIdx.x] = bs;
    }
}

// ---------------------------------------------------------------------------
// Kernel 3: reduce partials -> mean (single block, fixed order, double accum)
// ---------------------------------------------------------------------------
__global__ void k_reduce(const float* __restrict__ partials, int n,
                         float* __restrict__ out, double inv_count) {
    __shared__ double sw[4];
    const int tid = threadIdx.x;
    double s = 0.0;
    for (int i = tid; i < n; i += 256) s += (double)partials[i];
#pragma unroll
    for (int off = 32; off > 0; off >>= 1) s += __shfl_down(s, off, 64);
    const int lane = tid & 63, wv = tid >> 6;
    if (lane == 0) sw[wv] = s;
    __syncthreads();
    if (tid == 0) out[0] = (float)(((sw[0] + sw[1]) + (sw[2] + sw[3])) * inv_count);
}

// ---------------------------------------------------------------------------
extern "C" void kernel_launch(void* const* d_in, const int* in_sizes, int n_in,
                              void* d_out, int out_size, void* d_ws, size_t ws_size,
                              hipStream_t stream) {
    const float* inp = (const float*)d_in[0];
    const float* tgt = (const float*)d_in[1];
    float* out = (float*)d_out;

    const int total = in_sizes[0];          // B*256*256
    const int nimg  = total / 65536;        // B = 8
    const int nblk1 = total / 1024;         // 512 blocks (masks, 4 px/thread)
    const int nblk2 = nimg * 32;            // 256 blocks (DT+loss, 8 rows each)

    char* ws = (char*)d_ws;
    u64*   mv    = (u64*)ws;                          // nimg*1024 u64 each
    u64*   ml    = mv + (size_t)nimg * 1024;
    float* parts = (float*)(ml + (size_t)nimg * 1024);

    k_masks  <<<nblk1, 256,  0, stream>>>(inp, tgt, mv, ml);
    k_dt_loss<<<nblk2, 1024, 0, stream>>>(inp, mv, ml, parts);
    k_reduce <<<1,     256,  0, stream>>>(parts, nblk2, out, 1.0 / (double)total);
}